// Round 6
// baseline (244.517 us; speedup 1.0000x reference)
//
#include <hip/hip_runtime.h>
#include <hip/hip_fp16.h>

typedef _Float16 half8_t __attribute__((ext_vector_type(8)));
typedef _Float16 half4_t __attribute__((ext_vector_type(4)));
typedef float f32x4 __attribute__((ext_vector_type(4)));

#define TILE 128
#define BK 32

__device__ __forceinline__ void gload_lds16(const void* g, void* l) {
    __builtin_amdgcn_global_load_lds(
        (const __attribute__((address_space(1))) void*)g,
        (__attribute__((address_space(3))) void*)l,
        16, 0, 0);
}

// ---------------- x fp32 -> fp16 (+ |c|^2 precompute in block 0) ----------------
__global__ __launch_bounds__(256) void cvt_f32_f16_kernel(
    const float* __restrict__ x, _Float16* __restrict__ xh, int n,
    const float* __restrict__ cb, float* __restrict__ c2) {
    int i = (blockIdx.x * 256 + threadIdx.x) * 4;
    if (i < n) {
        float4 v = *(const float4*)(x + i);
        half4_t h;
        h[0] = (_Float16)v.x; h[1] = (_Float16)v.y;
        h[2] = (_Float16)v.z; h[3] = (_Float16)v.w;
        *(half4_t*)(xh + i) = h;
    }
    if (blockIdx.x == 0) {
        const float* cp = cb + threadIdx.x * 8;
        float4 a = *(const float4*)cp;
        float4 b = *(const float4*)(cp + 4);
        float s = a.x * a.x;
        s = fmaf(a.y, a.y, s); s = fmaf(a.z, a.z, s); s = fmaf(a.w, a.w, s);
        s = fmaf(b.x, b.x, s); s = fmaf(b.y, b.y, s); s = fmaf(b.z, b.z, s);
        s = fmaf(b.w, b.w, s);
        c2[threadIdx.x] = s;
    }
}

// ---------------- PQ quantize: weight -> wq (fp16) ----------------
// v5: NG=2 (1024 blocks -> 4 waves/SIMD), codebook + |c|^2 via uniform
// s_load (scalar cache), amortized over 2 groups: ~2 SMEM instrs per
// 26-instr VALU body per k. Top-2 value+index tracking; near-tie (gap <
// 5e-4) resolved by exact fp64 compare of the two candidates.
__global__ __launch_bounds__(256) void pq_quant_kernel(
    const float* __restrict__ W, const float* __restrict__ cb,
    const float* __restrict__ c2g, const float* __restrict__ rs,
    _Float16* __restrict__ wq, int groups_per_row) {
    int tid = threadIdx.x;
    const int NG = 2;
    int gbase = blockIdx.x * (256 * NG) + tid;

    float gv[NG][8];
    float rscale[NG];
#pragma unroll
    for (int j = 0; j < NG; j++) {
        int g = gbase + j * 256;
        int o = g / groups_per_row;
        float rsv = rs[o];
        rscale[j] = rsv;
        float rinv = 1.0f / rsv;
        const float* wp = W + (size_t)g * 8;
        float4 w0 = *(const float4*)wp;
        float4 w1 = *(const float4*)(wp + 4);
        gv[j][0] = w0.x * rinv; gv[j][1] = w0.y * rinv;
        gv[j][2] = w0.z * rinv; gv[j][3] = w0.w * rinv;
        gv[j][4] = w1.x * rinv; gv[j][5] = w1.y * rinv;
        gv[j][6] = w1.z * rinv; gv[j][7] = w1.w * rinv;
    }

    float best[NG], sec[NG];
    int bidx[NG], sidx[NG];
#pragma unroll
    for (int j = 0; j < NG; j++) {
        best[j] = 1e30f; sec[j] = 1e30f; bidx[j] = 0; sidx[j] = 0;
    }

#pragma unroll 2
    for (int k = 0; k < 256; k++) {
        const float* cp = cb + k * 8;               // uniform -> s_load
        float c0 = cp[0], c1 = cp[1], c2v = cp[2], c3 = cp[3];
        float c4 = cp[4], c5 = cp[5], c6 = cp[6], c7 = cp[7];
        float cc = c2g[k];                          // uniform -> s_load
#pragma unroll
        for (int j = 0; j < NG; j++) {
            float dot = gv[j][0] * c0;
            dot = fmaf(gv[j][1], c1, dot);
            dot = fmaf(gv[j][2], c2v, dot);
            dot = fmaf(gv[j][3], c3, dot);
            dot = fmaf(gv[j][4], c4, dot);
            dot = fmaf(gv[j][5], c5, dot);
            dot = fmaf(gv[j][6], c6, dot);
            dot = fmaf(gv[j][7], c7, dot);
            float s = fmaf(dot, -2.0f, cc);         // |c|^2 - 2 g.c
            bool lb = s < best[j];
            bool ls = s < sec[j];
            sidx[j] = lb ? bidx[j] : (ls ? k : sidx[j]);
            sec[j] = __builtin_amdgcn_fmed3f(s, best[j], sec[j]);
            bidx[j] = lb ? k : bidx[j];
            best[j] = fminf(s, best[j]);
        }
    }

#pragma unroll
    for (int j = 0; j < NG; j++) {
        int g = gbase + j * 256;
        int bi = bidx[j];
        if (sec[j] - best[j] < 5e-4f) {
            const float* wp = W + (size_t)g * 8;
            double gd[8];
            double rsd = (double)rscale[j];
#pragma unroll
            for (int i = 0; i < 8; i++) gd[i] = (double)wp[i] / rsd;
            const float* cbp = cb + bi * 8;
            const float* csp = cb + sidx[j] * 8;
            double db = 0.0, ds = 0.0;
#pragma unroll
            for (int i = 0; i < 8; i++) {
                double d = gd[i] - (double)cbp[i];
                db = fma(d, d, db);
            }
#pragma unroll
            for (int i = 0; i < 8; i++) {
                double d = gd[i] - (double)csp[i];
                ds = fma(d, d, ds);
            }
            if (ds < db || (ds == db && sidx[j] < bi)) bi = sidx[j];
        }
        const float* c = cb + bi * 8;
        float rsv = rscale[j];
        half8_t outv;
#pragma unroll
        for (int i = 0; i < 8; i++) outv[i] = (_Float16)(c[i] * rsv);
        *(half8_t*)(wq + (size_t)g * 8) = outv;
    }
}

// ---------------- GEMM: C[M][N] = A[M][K] @ B[N][K]^T (+ bias) ----------------
// fp16 MFMA 16x16x32, 128x128 tile, 4 waves each 64x64, BK=32,
// global_load_lds width-16 staging. Split-K via gridDim.z: kz==0 stores to
// C0 (+bias), kz==1 stores to C1 partial (no atomics). [R4-proven]
__global__ __launch_bounds__(256) void gemm_f16_kernel(
    const _Float16* __restrict__ A, const _Float16* __restrict__ B,
    const float* __restrict__ bias, float* __restrict__ C0,
    float* __restrict__ C1, int M, int N, int K, int Ksplit) {
    __shared__ _Float16 sA[TILE * BK];
    __shared__ _Float16 sB[TILE * BK];
    int tid = threadIdx.x;
    int wave = tid >> 6, lane = tid & 63;
    int wm = wave >> 1, wn = wave & 1;
    int bm = blockIdx.y * TILE, bn = blockIdx.x * TILE;
    int kz = blockIdx.z;
    int kbase = kz * Ksplit;

    f32x4 acc[4][4] = {};

    int srow = wave * 16 + (lane >> 2);
    int skc = (lane & 3) * 8;

    const int kIters = Ksplit / BK;
    for (int kt = 0; kt < kIters; kt++) {
        int k0 = kbase + kt * BK;
        __syncthreads();
#pragma unroll
        for (int j = 0; j < 2; j++) {
            int row = j * 64 + srow;
            int ldsbase = (j * 64 + wave * 16) * BK;
            gload_lds16(A + (size_t)(bm + row) * K + k0 + skc, &sA[ldsbase]);
            gload_lds16(B + (size_t)(bn + row) * K + k0 + skc, &sB[ldsbase]);
        }
        __syncthreads();

        half8_t a[4], b[4];
#pragma unroll
        for (int mt = 0; mt < 4; mt++)
            a[mt] = *(const half8_t*)&sA[(wm * 64 + mt * 16 + (lane & 15)) * BK + (lane >> 4) * 8];
#pragma unroll
        for (int nt = 0; nt < 4; nt++)
            b[nt] = *(const half8_t*)&sB[(wn * 64 + nt * 16 + (lane & 15)) * BK + (lane >> 4) * 8];
#pragma unroll
        for (int mt = 0; mt < 4; mt++)
#pragma unroll
            for (int nt = 0; nt < 4; nt++)
                acc[mt][nt] = __builtin_amdgcn_mfma_f32_16x16x32_f16(
                    a[mt], b[nt], acc[mt][nt], 0, 0, 0);
    }

    float* C = (kz == 0) ? C0 : C1;
    int col_base = bn + wn * 64;
    int row_base = bm + wm * 64;
#pragma unroll
    for (int nt = 0; nt < 4; nt++) {
        int col = col_base + nt * 16 + (lane & 15);
        float bv = (kz == 0) ? bias[col] : 0.0f;
#pragma unroll
        for (int mt = 0; mt < 4; mt++) {
            int r0 = row_base + mt * 16 + (lane >> 4) * 4;
#pragma unroll
            for (int r = 0; r < 4; r++)
                C[(size_t)(r0 + r) * N + col] = acc[mt][nt][r] + bv;
        }
    }
}

// ---------------- out += partial ----------------
__global__ __launch_bounds__(256) void reduce_add_kernel(
    float* __restrict__ out, const float* __restrict__ part, int n) {
    int i = (blockIdx.x * 256 + threadIdx.x) * 4;
    if (i < n) {
        float4 a = *(const float4*)(out + i);
        float4 b = *(const float4*)(part + i);
        a.x += b.x; a.y += b.y; a.z += b.z; a.w += b.w;
        *(float4*)(out + i) = a;
    }
}

extern "C" void kernel_launch(void* const* d_in, const int* in_sizes, int n_in,
                              void* d_out, int out_size, void* d_ws, size_t ws_size,
                              hipStream_t stream) {
    const float* x        = (const float*)d_in[0];
    const float* weight   = (const float*)d_in[1];
    const float* codebook = (const float*)d_in[2];
    const float* rowscale = (const float*)d_in[3];
    const float* bias     = (const float*)d_in[4];
    float* out = (float*)d_out;

    int O = in_sizes[3];          // row_scale has O elements
    int I = in_sizes[1] / O;      // weight is O*I
    int M = in_sizes[0] / I;      // x is (B*S)*I
    const int D = 8;
    int n_groups = O * I / D;

    size_t off = 0;
    _Float16* xh = (_Float16*)d_ws;                off += (size_t)M * I * sizeof(_Float16);
    _Float16* wq = (_Float16*)((char*)d_ws + off); off += (size_t)O * I * sizeof(_Float16);
    float* c2   = (float*)((char*)d_ws + off);     off += 4096;  // 256 floats, padded
    float* part = (float*)((char*)d_ws + off);
    size_t part_bytes = (size_t)M * O * sizeof(float);
    bool splitk = (ws_size >= off + part_bytes);

    int n_x = M * I;
    cvt_f32_f16_kernel<<<(n_x / 4 + 255) / 256, 256, 0, stream>>>(
        x, xh, n_x, codebook, c2);
    pq_quant_kernel<<<n_groups / 512, 256, 0, stream>>>(
        weight, codebook, c2, rowscale, wq, I / D);

    if (splitk) {
        gemm_f16_kernel<<<dim3(O / TILE, M / TILE, 2), 256, 0, stream>>>(
            xh, wq, bias, out, part, M, O, I, I / 2);
        reduce_add_kernel<<<(M * O / 4 + 255) / 256, 256, 0, stream>>>(
            out, part, M * O);
    } else {
        gemm_f16_kernel<<<dim3(O / TILE, M / TILE, 1), 256, 0, stream>>>(
            xh, wq, bias, out, part, M, O, I, I);
    }
}

// Round 7
// 235.937 us; speedup vs baseline: 1.0364x; 1.0364x over previous
//
#include <hip/hip_runtime.h>
#include <hip/hip_fp16.h>

typedef _Float16 half8_t __attribute__((ext_vector_type(8)));
typedef _Float16 half4_t __attribute__((ext_vector_type(4)));
typedef float f32x4 __attribute__((ext_vector_type(4)));
typedef float f32x2 __attribute__((ext_vector_type(2)));

#define TILE 128
#define BK 32

__device__ __forceinline__ void gload_lds16(const void* g, void* l) {
    __builtin_amdgcn_global_load_lds(
        (const __attribute__((address_space(1))) void*)g,
        (__attribute__((address_space(3))) void*)l,
        16, 0, 0);
}

// ---------------- fused: PQ quantize (blocks [0,n_pq)) + x cast (rest) ----
// pq v6: NG=2, __launch_bounds__(256,4) -> 128-VGPR budget (kill the remat
// that VGPR=32 forced in v5). Dot via f32x2 pk-fma. Codebook rows via
// uniform s_load; |c|^2 per block in LDS (uniform ds_read broadcast).
// Top-2 value+index; near-tie (gap<5e-4) -> fp64 compare of the two
// candidates in SCALED form sum((w - rs*c)^2) = rs^2 * original (rs>0,
// ordering identical) -- no fp64 divides.
__global__ __launch_bounds__(256, 4) void pq_cvt_kernel(
    const float* __restrict__ W, const float* __restrict__ cb,
    const float* __restrict__ rs, _Float16* __restrict__ wq,
    const float* __restrict__ x, _Float16* __restrict__ xh,
    int n_x, int groups_per_row, int n_pq_blocks) {
    __shared__ float c2s[256];
    int tid = threadIdx.x;
    int bid = blockIdx.x;

    if (bid >= n_pq_blocks) {           // ---- cvt part ----
        int i = ((bid - n_pq_blocks) * 256 + tid) * 4;
        if (i < n_x) {
            float4 v = *(const float4*)(x + i);
            half4_t h;
            h[0] = (_Float16)v.x; h[1] = (_Float16)v.y;
            h[2] = (_Float16)v.z; h[3] = (_Float16)v.w;
            *(half4_t*)(xh + i) = h;
        }
        return;
    }

    // ---- pq part ----
    {   // |c|^2 per codeword into LDS (one per thread)
        const float* cp = cb + tid * 8;
        float4 a = *(const float4*)cp;
        float4 b = *(const float4*)(cp + 4);
        float s = a.x * a.x;
        s = fmaf(a.y, a.y, s); s = fmaf(a.z, a.z, s); s = fmaf(a.w, a.w, s);
        s = fmaf(b.x, b.x, s); s = fmaf(b.y, b.y, s); s = fmaf(b.z, b.z, s);
        s = fmaf(b.w, b.w, s);
        c2s[tid] = s;
    }
    __syncthreads();

    const int NG = 2;
    int gbase = bid * (256 * NG) + tid;

    f32x2 gv[NG][4];
    float rscale[NG];
#pragma unroll
    for (int j = 0; j < NG; j++) {
        int g = gbase + j * 256;
        int o = g / groups_per_row;
        float rsv = rs[o];
        rscale[j] = rsv;
        float rinv = 1.0f / rsv;
        const float* wp = W + (size_t)g * 8;
        float4 w0 = *(const float4*)wp;
        float4 w1 = *(const float4*)(wp + 4);
        gv[j][0][0] = w0.x * rinv; gv[j][0][1] = w0.y * rinv;
        gv[j][1][0] = w0.z * rinv; gv[j][1][1] = w0.w * rinv;
        gv[j][2][0] = w1.x * rinv; gv[j][2][1] = w1.y * rinv;
        gv[j][3][0] = w1.z * rinv; gv[j][3][1] = w1.w * rinv;
    }

    float best[NG], sec[NG];
    int bidx[NG], sidx[NG];
#pragma unroll
    for (int j = 0; j < NG; j++) {
        best[j] = 1e30f; sec[j] = 1e30f; bidx[j] = 0; sidx[j] = 0;
    }

#pragma unroll 2
    for (int k = 0; k < 256; k++) {
        const f32x2* cp2 = (const f32x2*)(cb + k * 8);  // uniform -> s_load
        f32x2 c01 = cp2[0], c23 = cp2[1], c45 = cp2[2], c67 = cp2[3];
        float cc = c2s[k];                               // uniform LDS bcast
#pragma unroll
        for (int j = 0; j < NG; j++) {
            f32x2 d2 = gv[j][0] * c01;
            d2 = __builtin_elementwise_fma(gv[j][1], c23, d2);
            d2 = __builtin_elementwise_fma(gv[j][2], c45, d2);
            d2 = __builtin_elementwise_fma(gv[j][3], c67, d2);
            float dot = d2[0] + d2[1];
            float s = fmaf(dot, -2.0f, cc);              // |c|^2 - 2 g.c
            bool lb = s < best[j];
            bool ls = s < sec[j];
            sidx[j] = lb ? bidx[j] : (ls ? k : sidx[j]);
            sec[j] = __builtin_amdgcn_fmed3f(s, best[j], sec[j]);
            bidx[j] = lb ? k : bidx[j];
            best[j] = fminf(s, best[j]);
        }
    }

#pragma unroll
    for (int j = 0; j < NG; j++) {
        int g = gbase + j * 256;
        int bi = bidx[j];
        if (sec[j] - best[j] < 5e-4f) {
            // scaled fp64 compare: sum((w - rs*c)^2), ordering == original
            const float* wp = W + (size_t)g * 8;
            const float* cbp = cb + bi * 8;
            const float* csp = cb + sidx[j] * 8;
            double rsd = (double)rscale[j];
            double db = 0.0, ds = 0.0;
#pragma unroll
            for (int i = 0; i < 8; i++) {
                double wd = (double)wp[i];
                double d1 = fma(-rsd, (double)cbp[i], wd);
                db = fma(d1, d1, db);
                double d2_ = fma(-rsd, (double)csp[i], wd);
                ds = fma(d2_, d2_, ds);
            }
            if (ds < db || (ds == db && sidx[j] < bi)) bi = sidx[j];
        }
        const float* c = cb + bi * 8;
        float rsv = rscale[j];
        half8_t outv;
#pragma unroll
        for (int i = 0; i < 8; i++) outv[i] = (_Float16)(c[i] * rsv);
        *(half8_t*)(wq + (size_t)g * 8) = outv;
    }
}

// ---------------- GEMM: C[M][N] = A[M][K] @ B[N][K]^T (+ bias) ----------------
// fp16 MFMA 16x16x32, 128x128 tile, 4 waves each 64x64, BK=32,
// global_load_lds width-16 staging. Split-K via gridDim.z: kz==0 stores to
// C0 (+bias), kz==1 stores to C1 partial (no atomics). [R4-proven]
__global__ __launch_bounds__(256) void gemm_f16_kernel(
    const _Float16* __restrict__ A, const _Float16* __restrict__ B,
    const float* __restrict__ bias, float* __restrict__ C0,
    float* __restrict__ C1, int M, int N, int K, int Ksplit) {
    __shared__ _Float16 sA[TILE * BK];
    __shared__ _Float16 sB[TILE * BK];
    int tid = threadIdx.x;
    int wave = tid >> 6, lane = tid & 63;
    int wm = wave >> 1, wn = wave & 1;
    int bm = blockIdx.y * TILE, bn = blockIdx.x * TILE;
    int kz = blockIdx.z;
    int kbase = kz * Ksplit;

    f32x4 acc[4][4] = {};

    int srow = wave * 16 + (lane >> 2);
    int skc = (lane & 3) * 8;

    const int kIters = Ksplit / BK;
    for (int kt = 0; kt < kIters; kt++) {
        int k0 = kbase + kt * BK;
        __syncthreads();
#pragma unroll
        for (int j = 0; j < 2; j++) {
            int row = j * 64 + srow;
            int ldsbase = (j * 64 + wave * 16) * BK;
            gload_lds16(A + (size_t)(bm + row) * K + k0 + skc, &sA[ldsbase]);
            gload_lds16(B + (size_t)(bn + row) * K + k0 + skc, &sB[ldsbase]);
        }
        __syncthreads();

        half8_t a[4], b[4];
#pragma unroll
        for (int mt = 0; mt < 4; mt++)
            a[mt] = *(const half8_t*)&sA[(wm * 64 + mt * 16 + (lane & 15)) * BK + (lane >> 4) * 8];
#pragma unroll
        for (int nt = 0; nt < 4; nt++)
            b[nt] = *(const half8_t*)&sB[(wn * 64 + nt * 16 + (lane & 15)) * BK + (lane >> 4) * 8];
#pragma unroll
        for (int mt = 0; mt < 4; mt++)
#pragma unroll
            for (int nt = 0; nt < 4; nt++)
                acc[mt][nt] = __builtin_amdgcn_mfma_f32_16x16x32_f16(
                    a[mt], b[nt], acc[mt][nt], 0, 0, 0);
    }

    float* C = (kz == 0) ? C0 : C1;
    int col_base = bn + wn * 64;
    int row_base = bm + wm * 64;
#pragma unroll
    for (int nt = 0; nt < 4; nt++) {
        int col = col_base + nt * 16 + (lane & 15);
        float bv = (kz == 0) ? bias[col] : 0.0f;
#pragma unroll
        for (int mt = 0; mt < 4; mt++) {
            int r0 = row_base + mt * 16 + (lane >> 4) * 4;
#pragma unroll
            for (int r = 0; r < 4; r++)
                C[(size_t)(r0 + r) * N + col] = acc[mt][nt][r] + bv;
        }
    }
}

// ---------------- out += partial ----------------
__global__ __launch_bounds__(256) void reduce_add_kernel(
    float* __restrict__ out, const float* __restrict__ part, int n) {
    int i = (blockIdx.x * 256 + threadIdx.x) * 4;
    if (i < n) {
        float4 a = *(const float4*)(out + i);
        float4 b = *(const float4*)(part + i);
        a.x += b.x; a.y += b.y; a.z += b.z; a.w += b.w;
        *(float4*)(out + i) = a;
    }
}

extern "C" void kernel_launch(void* const* d_in, const int* in_sizes, int n_in,
                              void* d_out, int out_size, void* d_ws, size_t ws_size,
                              hipStream_t stream) {
    const float* x        = (const float*)d_in[0];
    const float* weight   = (const float*)d_in[1];
    const float* codebook = (const float*)d_in[2];
    const float* rowscale = (const float*)d_in[3];
    const float* bias     = (const float*)d_in[4];
    float* out = (float*)d_out;

    int O = in_sizes[3];          // row_scale has O elements
    int I = in_sizes[1] / O;      // weight is O*I
    int M = in_sizes[0] / I;      // x is (B*S)*I
    const int D = 8;
    int n_groups = O * I / D;

    size_t off = 0;
    _Float16* xh = (_Float16*)d_ws;                off += (size_t)M * I * sizeof(_Float16);
    _Float16* wq = (_Float16*)((char*)d_ws + off); off += (size_t)O * I * sizeof(_Float16);
    float* part = (float*)((char*)d_ws + off);
    size_t part_bytes = (size_t)M * O * sizeof(float);
    bool splitk = (ws_size >= off + part_bytes);

    int n_x = M * I;
    int n_pq_blocks = n_groups / 512;
    int n_cvt_blocks = (n_x / 4 + 255) / 256;
    pq_cvt_kernel<<<n_pq_blocks + n_cvt_blocks, 256, 0, stream>>>(
        weight, codebook, rowscale, wq, x, xh, n_x, I / D, n_pq_blocks);

    if (splitk) {
        gemm_f16_kernel<<<dim3(O / TILE, M / TILE, 2), 256, 0, stream>>>(
            xh, wq, bias, out, part, M, O, I, I / 2);
        reduce_add_kernel<<<(M * O / 4 + 255) / 256, 256, 0, stream>>>(
            out, part, M * O);
    } else {
        gemm_f16_kernel<<<dim3(O / TILE, M / TILE, 1), 256, 0, stream>>>(
            xh, wq, bias, out, part, M, O, I, I);
    }
}

// Round 8
// 208.552 us; speedup vs baseline: 1.1725x; 1.1313x over previous
//
#include <hip/hip_runtime.h>
#include <hip/hip_fp16.h>

typedef _Float16 half8_t __attribute__((ext_vector_type(8)));
typedef _Float16 half4_t __attribute__((ext_vector_type(4)));
typedef float f32x4 __attribute__((ext_vector_type(4)));

#define TILE 128
#define BK 32

__device__ __forceinline__ void gload_lds16(const void* g, void* l) {
    __builtin_amdgcn_global_load_lds(
        (const __attribute__((address_space(1))) void*)g,
        (__attribute__((address_space(3))) void*)l,
        16, 0, 0);
}

// ---------------- fused: PQ quantize (blocks [0,n_pq)) + x cast (rest) ----
// pq v7 (MFMA): scores S[cw][grp] = |c|^2 - 2 g.c via mfma_f32_16x16x32_f16.
// K=32 packed as A(codewords)=[ch,cl,ch,cl], B(groups)=[gh,gh,gl,gl] where
// ch+cl = fp16-split of -2c and gh+gl = fp16-split of g: products are exact
// in fp32, so the score matches the fp32 formula to ~1e-6. acc is seeded
// with |c|^2 so the MFMA emits scores directly. D-layout: row(codeword)=
// (lane>>4)*4+r, col(group)=lane&15 -> each lane tracks top-2 for ONE group
// over 4 codewords/tile; 16 tiles cover 256 codewords; 2 shfl-xor steps
// merge the 4 quads. Near-tie (gap<5e-4): fp64 compare of the two
// candidates in scaled form sum((w - rs*c)^2) — same semantics as R4-R7.
__global__ __launch_bounds__(256, 4) void pq_cvt_kernel(
    const float* __restrict__ W, const float* __restrict__ cbg,
    const float* __restrict__ rs, _Float16* __restrict__ wq,
    const float* __restrict__ x, _Float16* __restrict__ xh,
    int n_x, int groups_per_row, int n_pq_blocks) {
    __shared__ __align__(16) _Float16 cbh[256 * 8];  // fp16(-2c)
    __shared__ __align__(16) _Float16 cbl[256 * 8];  // fp16(-2c - cbh)
    __shared__ __align__(16) float    c2s[256];      // |c|^2
    __shared__ __align__(16) _Float16 ghb[64 * 8];   // fp16(g)
    __shared__ __align__(16) _Float16 glb[64 * 8];   // fp16(g - ghb)

    int tid = threadIdx.x;
    int bid = blockIdx.x;

    if (bid >= n_pq_blocks) {           // ---- cvt part ----
        int i = ((bid - n_pq_blocks) * 256 + tid) * 4;
        if (i < n_x) {
            float4 v = *(const float4*)(x + i);
            half4_t h;
            h[0] = (_Float16)v.x; h[1] = (_Float16)v.y;
            h[2] = (_Float16)v.z; h[3] = (_Float16)v.w;
            *(half4_t*)(xh + i) = h;
        }
        return;
    }

    // ---- pq part: this block owns 64 consecutive groups (one rs row chunk)
    int gblock = bid * 64;
    float rsv = rs[gblock / groups_per_row];   // uniform: 64 | groups_per_row
    float rinv = 1.0f / rsv;

    {   // stage codebook: thread k handles codeword k
        const float4* cp4 = (const float4*)(cbg + tid * 8);
        float4 ca = cp4[0], cb4 = cp4[1];
        float cv[8] = {ca.x, ca.y, ca.z, ca.w, cb4.x, cb4.y, cb4.z, cb4.w};
        float c2 = 0.0f;
#pragma unroll
        for (int i = 0; i < 8; i++) {
            float c = cv[i];
            c2 = fmaf(c, c, c2);
            float m = -2.0f * c;
            _Float16 h = (_Float16)m;
            cbh[tid * 8 + i] = h;
            cbl[tid * 8 + i] = (_Float16)(m - (float)h);
        }
        c2s[tid] = c2;
    }
    {   // stage this block's 64 groups (2 elems/thread, coalesced)
        const float* wp = W + (size_t)gblock * 8;
        float2 v2 = *(const float2*)(wp + tid * 2);
        float v0 = v2.x * rinv, v1 = v2.y * rinv;
        _Float16 h0 = (_Float16)v0, h1 = (_Float16)v1;
        ghb[tid * 2]     = h0;
        ghb[tid * 2 + 1] = h1;
        glb[tid * 2]     = (_Float16)(v0 - (float)h0);
        glb[tid * 2 + 1] = (_Float16)(v1 - (float)h1);
    }
    __syncthreads();

    int wave = tid >> 6, lane = tid & 63;
    int q = lane >> 4, n15 = lane & 15;

    // B-frag (groups): B[k=q*8+j][n] -> quads 0,1: gh ; quads 2,3: gl
    const _Float16* gsrc = (q < 2) ? ghb : glb;
    half8_t bfrag = *(const half8_t*)&gsrc[(wave * 16 + n15) * 8];

    // A-frag (codewords): A[m=n15][k=q*8+j] -> quads 0,2: ch ; 1,3: cl
    const _Float16* asrc = (q & 1) ? cbl : cbh;

    float best = 1e30f, sec = 1e30f;
    int bidx = 0, sidx = 0;
    int cw0 = q * 4;                    // this lane's codeword-row base

#pragma unroll 4
    for (int t = 0; t < 16; t++) {
        half8_t afrag = *(const half8_t*)&asrc[(t * 16 + n15) * 8];
        f32x4 cc = *(const f32x4*)&c2s[t * 16 + q * 4];
        f32x4 d = __builtin_amdgcn_mfma_f32_16x16x32_f16(afrag, bfrag, cc, 0, 0, 0);
#pragma unroll
        for (int r = 0; r < 4; r++) {
            float s = d[r];
            int cw = t * 16 + cw0 + r;
            bool lb = s < best;
            bool ls = s < sec;
            sidx = lb ? bidx : (ls ? cw : sidx);
            sec = __builtin_amdgcn_fmed3f(s, best, sec);
            bidx = lb ? cw : bidx;
            best = fminf(s, best);
        }
    }

    // merge the 4 quads (same group col, different codeword rows)
#pragma unroll
    for (int mstep = 0; mstep < 2; mstep++) {
        int mask = 16 << mstep;
        float ob = __shfl_xor(best, mask, 64);
        float os = __shfl_xor(sec, mask, 64);
        int obi = __shfl_xor(bidx, mask, 64);
        int osi = __shfl_xor(sidx, mask, 64);
        bool sw = ob < best;
        float nb = fminf(best, ob);
        int nbi = sw ? obi : bidx;
        float m1 = fmaxf(best, ob);     // loser of the firsts
        int m1i = sw ? bidx : obi;
        bool sw2 = os < sec;
        float m2 = fminf(sec, os);      // winner of the seconds
        int m2i = sw2 ? osi : sidx;
        bool sw3 = m2 < m1;
        best = nb; bidx = nbi;
        sec = fminf(m1, m2);
        sidx = sw3 ? m2i : m1i;
    }

    if (q == 0) {                        // lanes 0-15 finalize one group each
        int g = gblock + wave * 16 + n15;
        int bi = bidx;
        if (sec - best < 5e-4f) {
            // scaled fp64 compare: sum((w - rs*c)^2), ordering == original
            const float* wp = W + (size_t)g * 8;
            const float* cbp = cbg + bi * 8;
            const float* csp = cbg + sidx * 8;
            double rsd = (double)rsv;
            double db = 0.0, ds = 0.0;
#pragma unroll
            for (int i = 0; i < 8; i++) {
                double wd = (double)wp[i];
                double d1 = fma(-rsd, (double)cbp[i], wd);
                db = fma(d1, d1, db);
                double d2_ = fma(-rsd, (double)csp[i], wd);
                ds = fma(d2_, d2_, ds);
            }
            if (ds < db || (ds == db && sidx < bi)) bi = sidx;
        }
        const float* c = cbg + bi * 8;
        half8_t outv;
#pragma unroll
        for (int i = 0; i < 8; i++) outv[i] = (_Float16)(c[i] * rsv);
        *(half8_t*)(wq + (size_t)g * 8) = outv;
    }
}

// ---------------- GEMM: C[M][N] = A[M][K] @ B[N][K]^T (+ bias) ----------------
// fp16 MFMA 16x16x32, 128x128 tile, 4 waves each 64x64, BK=32,
// global_load_lds width-16 staging. Split-K via gridDim.z: kz==0 stores to
// C0 (+bias), kz==1 stores to C1 partial (no atomics). [R4-proven]
__global__ __launch_bounds__(256) void gemm_f16_kernel(
    const _Float16* __restrict__ A, const _Float16* __restrict__ B,
    const float* __restrict__ bias, float* __restrict__ C0,
    float* __restrict__ C1, int M, int N, int K, int Ksplit) {
    __shared__ _Float16 sA[TILE * BK];
    __shared__ _Float16 sB[TILE * BK];
    int tid = threadIdx.x;
    int wave = tid >> 6, lane = tid & 63;
    int wm = wave >> 1, wn = wave & 1;
    int bm = blockIdx.y * TILE, bn = blockIdx.x * TILE;
    int kz = blockIdx.z;
    int kbase = kz * Ksplit;

    f32x4 acc[4][4] = {};

    int srow = wave * 16 + (lane >> 2);
    int skc = (lane & 3) * 8;

    const int kIters = Ksplit / BK;
    for (int kt = 0; kt < kIters; kt++) {
        int k0 = kbase + kt * BK;
        __syncthreads();
#pragma unroll
        for (int j = 0; j < 2; j++) {
            int row = j * 64 + srow;
            int ldsbase = (j * 64 + wave * 16) * BK;
            gload_lds16(A + (size_t)(bm + row) * K + k0 + skc, &sA[ldsbase]);
            gload_lds16(B + (size_t)(bn + row) * K + k0 + skc, &sB[ldsbase]);
        }
        __syncthreads();

        half8_t a[4], b[4];
#pragma unroll
        for (int mt = 0; mt < 4; mt++)
            a[mt] = *(const half8_t*)&sA[(wm * 64 + mt * 16 + (lane & 15)) * BK + (lane >> 4) * 8];
#pragma unroll
        for (int nt = 0; nt < 4; nt++)
            b[nt] = *(const half8_t*)&sB[(wn * 64 + nt * 16 + (lane & 15)) * BK + (lane >> 4) * 8];
#pragma unroll
        for (int mt = 0; mt < 4; mt++)
#pragma unroll
            for (int nt = 0; nt < 4; nt++)
                acc[mt][nt] = __builtin_amdgcn_mfma_f32_16x16x32_f16(
                    a[mt], b[nt], acc[mt][nt], 0, 0, 0);
    }

    float* C = (kz == 0) ? C0 : C1;
    int col_base = bn + wn * 64;
    int row_base = bm + wm * 64;
#pragma unroll
    for (int nt = 0; nt < 4; nt++) {
        int col = col_base + nt * 16 + (lane & 15);
        float bv = (kz == 0) ? bias[col] : 0.0f;
#pragma unroll
        for (int mt = 0; mt < 4; mt++) {
            int r0 = row_base + mt * 16 + (lane >> 4) * 4;
#pragma unroll
            for (int r = 0; r < 4; r++)
                C[(size_t)(r0 + r) * N + col] = acc[mt][nt][r] + bv;
        }
    }
}

// ---------------- out += partial ----------------
__global__ __launch_bounds__(256) void reduce_add_kernel(
    float* __restrict__ out, const float* __restrict__ part, int n) {
    int i = (blockIdx.x * 256 + threadIdx.x) * 4;
    if (i < n) {
        float4 a = *(const float4*)(out + i);
        float4 b = *(const float4*)(part + i);
        a.x += b.x; a.y += b.y; a.z += b.z; a.w += b.w;
        *(float4*)(out + i) = a;
    }
}

extern "C" void kernel_launch(void* const* d_in, const int* in_sizes, int n_in,
                              void* d_out, int out_size, void* d_ws, size_t ws_size,
                              hipStream_t stream) {
    const float* x        = (const float*)d_in[0];
    const float* weight   = (const float*)d_in[1];
    const float* codebook = (const float*)d_in[2];
    const float* rowscale = (const float*)d_in[3];
    const float* bias     = (const float*)d_in[4];
    float* out = (float*)d_out;

    int O = in_sizes[3];          // row_scale has O elements
    int I = in_sizes[1] / O;      // weight is O*I
    int M = in_sizes[0] / I;      // x is (B*S)*I
    const int D = 8;
    int n_groups = O * I / D;

    size_t off = 0;
    _Float16* xh = (_Float16*)d_ws;                off += (size_t)M * I * sizeof(_Float16);
    _Float16* wq = (_Float16*)((char*)d_ws + off); off += (size_t)O * I * sizeof(_Float16);
    float* part = (float*)((char*)d_ws + off);
    size_t part_bytes = (size_t)M * O * sizeof(float);
    bool splitk = (ws_size >= off + part_bytes);

    int n_x = M * I;
    int n_pq_blocks = n_groups / 64;
    int n_cvt_blocks = (n_x / 4 + 255) / 256;
    pq_cvt_kernel<<<n_pq_blocks + n_cvt_blocks, 256, 0, stream>>>(
        weight, codebook, rowscale, wq, x, xh, n_x, I / D, n_pq_blocks);

    if (splitk) {
        gemm_f16_kernel<<<dim3(O / TILE, M / TILE, 2), 256, 0, stream>>>(
            xh, wq, bias, out, part, M, O, I, I / 2);
        reduce_add_kernel<<<(M * O / 4 + 255) / 256, 256, 0, stream>>>(
            out, part, M * O);
    } else {
        gemm_f16_kernel<<<dim3(O / TILE, M / TILE, 1), 256, 0, stream>>>(
            xh, wq, bias, out, part, M, O, I, I);
    }
}